// Round 9
// baseline (612.995 us; speedup 1.0000x reference)
//
#include <hip/hip_runtime.h>
#include <hip/hip_bf16.h>

#define BN 2
#define C0 64
#define HH 160
#define WW 160
#define HWn (HH*WW)          // 25600
#define PN (BN*HWn)          // 51200
#define DWCH 128
#define OMC 108
#define PPB 64
#define NB (PN/PPB)          // 800

#define S128 ((long)PN*128)
#define S108 ((long)PN*108)
#define S64v ((long)PN*64)

// ---- phase-1 weight pack (lives in fR region; fR written only by side-1 k_outp)
#define W1_PW1T   0        // [64c][128o] pw1_w * ln1_g[c], transposed
#define W1_RS1    8192     // [128] rowsum of pw1T over c
#define W1_PB1    8320     // [128]
#define W1_VALT   8448     // [128c][128o]
#define W1_VB     24832    // [128]
#define W1_DWC    24960    // [1152]
#define W1_DWB    26112    // [128]
#define W1_OMT    26240    // [128c][108o]
#define W1_OMB    40064    // [108]
#define W1_OUTT   40172    // [128c][128o]
#define W1_OUTB   56556    // [128]
// ---- phase-2 weight pack (Bv+26000; v dead after side-1 k_samp8)
#define WB_OUTT   0        // [128c][128o]
#define WB_OUTB   16384
#define WB_C3T    16512    // [128c][64o]
#define WB_C3B    24704
#define WB_BETA   24768
#define WB_W4T    24832    // [128c][128o] conv4_w * norm2_g[c], transposed
#define WB_RS4    41216
#define WB_B4     41344
#define WB_W5T    41472    // [64c][64o] conv5_w * gamma[o], transposed
#define WB_B5G    45568    // [64] conv5_b * gamma

__device__ __forceinline__ float ldin(const void* p, long i, int bf) {
  return bf ? __bfloat162float(((const __hip_bfloat16*)p)[i])
            : ((const float*)p)[i];
}
__device__ __forceinline__ void stout(void* p, long i, float v, int bf) {
  if (bf) ((__hip_bfloat16*)p)[i] = __float2bfloat16(v);
  else    ((float*)p)[i] = v;
}

// ---- weight conversion, phase 1 (into fR region); also publishes dtype flag
__global__ void k_conv1(const void* pw1_w, const void* ln1_g, const void* pw1_b,
                        const void* val_w, const void* val_b,
                        const void* dwc_w, const void* dwc_b,
                        const void* om_w, const void* om_b,
                        const void* outp_w, const void* outp_b,
                        float* __restrict__ W, int* flag) {
  const int bf = (*(const unsigned*)ln1_g == 0x3F800000u) ? 0 : 1;
  if (blockIdx.x == 0 && threadIdx.x == 0) *flag = bf;
  const int g0 = blockIdx.x*256 + threadIdx.x, GS = gridDim.x*256;
  for (int i = g0; i < 8192; i += GS) { int c = i>>7, o = i&127;
    W[W1_PW1T + i] = ldin(pw1_w, o*64 + c, bf) * ldin(ln1_g, c, bf); }
  for (int o = g0; o < 128; o += GS) { float s = 0.f;
    for (int c = 0; c < 64; ++c) s += ldin(pw1_w, o*64+c, bf) * ldin(ln1_g, c, bf);
    W[W1_RS1 + o] = s; W[W1_PB1 + o] = ldin(pw1_b, o, bf); }
  for (int i = g0; i < 16384; i += GS) { int c = i>>7, o = i&127;
    W[W1_VALT + i] = ldin(val_w, o*128 + c, bf); }
  for (int i = g0; i < 128; i += GS) W[W1_VB + i] = ldin(val_b, i, bf);
  for (int i = g0; i < 1152; i += GS) W[W1_DWC + i] = ldin(dwc_w, i, bf);
  for (int i = g0; i < 128; i += GS) W[W1_DWB + i] = ldin(dwc_b, i, bf);
  for (int i = g0; i < 13824; i += GS) { int c = i/108, o = i%108;
    W[W1_OMT + i] = ldin(om_w, o*128 + c, bf); }
  for (int i = g0; i < 108; i += GS) W[W1_OMB + i] = ldin(om_b, i, bf);
  for (int i = g0; i < 16384; i += GS) { int c = i>>7, o = i&127;
    W[W1_OUTT + i] = ldin(outp_w, o*128 + c, bf); }
  for (int i = g0; i < 128; i += GS) W[W1_OUTB + i] = ldin(outp_b, i, bf);
}

// ---- weight conversion, phase 2 (into Bv+26000)
__global__ void k_conv2(const void* outp_w, const void* outp_b,
                        const void* conv3_w, const void* conv3_b, const void* beta,
                        const void* norm2_g, const void* conv4_w, const void* conv4_b,
                        const void* conv5_w, const void* conv5_b, const void* gamma,
                        float* __restrict__ W, const int* flagp) {
  const int bf = *flagp;
  const int g0 = blockIdx.x*256 + threadIdx.x, GS = gridDim.x*256;
  for (int i = g0; i < 16384; i += GS) { int c = i>>7, o = i&127;
    W[WB_OUTT + i] = ldin(outp_w, o*128 + c, bf); }
  for (int i = g0; i < 128; i += GS) W[WB_OUTB + i] = ldin(outp_b, i, bf);
  for (int i = g0; i < 8192; i += GS) { int c = i>>6, o = i&63;
    W[WB_C3T + i] = ldin(conv3_w, o*128 + c, bf); }
  for (int i = g0; i < 64; i += GS) { W[WB_C3B + i] = ldin(conv3_b, i, bf);
    W[WB_BETA + i] = ldin(beta, i, bf); }
  for (int i = g0; i < 16384; i += GS) { int c = i>>7, o = i&127;
    W[WB_W4T + i] = ldin(conv4_w, o*128 + c, bf) * ldin(norm2_g, c, bf); }
  for (int o = g0; o < 128; o += GS) { float s = 0.f;
    for (int c = 0; c < 128; ++c) s += ldin(conv4_w, o*128+c, bf) * ldin(norm2_g, c, bf);
    W[WB_RS4 + o] = s; W[WB_B4 + o] = ldin(conv4_b, o, bf); }
  for (int i = g0; i < 4096; i += GS) { int c = i>>6, o = i&63;
    W[WB_W5T + i] = ldin(conv5_w, o*64 + c, bf) * ldin(gamma, o, bf); }
  for (int i = g0; i < 64; i += GS)
    W[WB_B5G + i] = ldin(conv5_b, i, bf) * ldin(gamma, i, bf);
}

// ---- 1. LN(64) + pw1 (64->128) + val (128->128) -> h1, v  [8 waves, 16 o/thread]
__global__ __launch_bounds__(512, 6) void k_lnpw1v(const void* x, const float* __restrict__ W,
                                                   float* __restrict__ h1, float* __restrict__ vout,
                                                   const int* flagp) {
  const int bf = *flagp;
  const int tid = threadIdx.x, lane = tid & 63;
  const int pbase = blockIdx.x * PPB;
  const int b = pbase / HWn, rem0 = pbase % HWn;
  __shared__ float buf[8256];   // raw x (stride 65) -> h1 (stride 129) -> v (stride 129)
  __shared__ float st[1152];    // ps[512], ps2[512], mean[64]@1024, rstd[64]@1088
  for (int it = 0; it < 8; ++it) {
    int idx = it*512 + tid;     // 4096 = 64c x 64p
    int c = idx >> 6, p = idx & 63;
    buf[p*65 + c] = ldin(x, (long)(b*C0 + c)*HWn + rem0 + p, bf);
  }
  __syncthreads();
  {
    int p = tid & 63, cg = tid >> 6;
    float s = 0.f, s2 = 0.f;
    #pragma unroll
    for (int j = 0; j < 8; ++j) { float v = buf[p*65 + cg*8 + j]; s += v; s2 += v*v; }
    st[cg*64 + p] = s; st[512 + cg*64 + p] = s2;
  }
  __syncthreads();
  if (tid < 64) {
    float s = 0.f, s2 = 0.f;
    #pragma unroll
    for (int cg = 0; cg < 8; ++cg) { s += st[cg*64 + tid]; s2 += st[512 + cg*64 + tid]; }
    float mean = s * (1.f/64.f);
    float rstd = rsqrtf(s2 * (1.f/64.f) - mean*mean + 1e-5f);
    st[1024 + tid] = mean; st[1088 + tid] = rstd;
  }
  __syncthreads();
  const int obase = __builtin_amdgcn_readfirstlane((tid >> 6) * 16);
  const float mean = st[1024 + lane], rstd = st[1088 + lane];
  float acc[16] = {};
  for (int c = 0; c < 64; ++c) {
    const float a = buf[lane*65 + c];
    const float* __restrict__ wr = W + W1_PW1T + c*128 + obase;
    #pragma unroll
    for (int oi = 0; oi < 16; ++oi) acc[oi] += a * wr[oi];
  }
  __syncthreads();   // all stride-65 reads done
  #pragma unroll
  for (int oi = 0; oi < 16; ++oi)
    buf[lane*129 + obase + oi] =
      rstd*(acc[oi] - mean*W[W1_RS1 + obase + oi]) + W[W1_PB1 + obase + oi];
  __syncthreads();
  for (int it = 0; it < 4; ++it) {
    int idx = it*512 + tid;     // 2048 f4
    int p = idx >> 5, c4 = idx & 31;
    const float* sp = &buf[p*129 + c4*4];
    *(float4*)&h1[(long)(pbase+p)*128 + c4*4] = make_float4(sp[0],sp[1],sp[2],sp[3]);
  }
  float acc2[16] = {};
  for (int c = 0; c < 128; ++c) {
    const float a = buf[lane*129 + c];
    const float* __restrict__ wr = W + W1_VALT + c*128 + obase;
    #pragma unroll
    for (int oi = 0; oi < 16; ++oi) acc2[oi] += a * wr[oi];
  }
  __syncthreads();
  #pragma unroll
  for (int oi = 0; oi < 16; ++oi)
    buf[lane*129 + obase + oi] = acc2[oi] + W[W1_VB + obase + oi];
  __syncthreads();
  for (int it = 0; it < 4; ++it) {
    int idx = it*512 + tid;
    int p = idx >> 5, c4 = idx & 31;
    const float* sp = &buf[p*129 + c4*4];
    *(float4*)&vout[(long)(pbase+p)*128 + c4*4] = make_float4(sp[0],sp[1],sp[2],sp[3]);
  }
}

// ---- 2. depthwise 3x3 (float4) + om head (128->108)  [8 waves, 14/13 o/thread]
__global__ __launch_bounds__(512, 6) void k_dwom4(const float* __restrict__ h1,
                                                  const float* __restrict__ W,
                                                  float* __restrict__ om) {
  const int tid = threadIdx.x, lane = tid & 63;
  const int pbase = blockIdx.x * PPB;
  const int b = pbase / HWn, rem0 = pbase % HWn;
  __shared__ float buf[8256];
  __shared__ float dww[1280];
  for (int i = tid; i < 1280; i += 512)
    dww[i] = (i < 1152) ? W[W1_DWC + i] : W[W1_DWB + i - 1152];
  __syncthreads();
  for (int it = 0; it < 4; ++it) {
    int idx = it*512 + tid;          // 2048 = 64 px x 32 ch4-slots
    int p = idx >> 5, c = (idx & 31)*4;
    int rem = rem0 + p, h = rem / WW, w2 = rem % WW;
    float4 a4 = *(const float4*)&dww[1152 + c];
    #pragma unroll
    for (int ky = 0; ky < 3; ++ky) {
      int hh = h + ky - 1;
      if (hh < 0 || hh >= HH) continue;
      #pragma unroll
      for (int kx = 0; kx < 3; ++kx) {
        int ww2 = w2 + kx - 1;
        if (ww2 < 0 || ww2 >= WW) continue;
        float4 hv = *(const float4*)&h1[(long)(b*HWn + hh*WW + ww2)*128 + c];
        float4 wv = *(const float4*)&dww[(ky*3+kx)*128 + c];
        a4.x += hv.x*wv.x; a4.y += hv.y*wv.y; a4.z += hv.z*wv.z; a4.w += hv.w*wv.w;
      }
    }
    float* d = &buf[p*129 + c];
    d[0]=a4.x; d[1]=a4.y; d[2]=a4.z; d[3]=a4.w;
  }
  __syncthreads();
  const int wv = tid >> 6;
  const int cnt = (wv < 4) ? 14 : 13;
  const int obase = __builtin_amdgcn_readfirstlane((wv < 4) ? wv*14 : 56 + (wv-4)*13);
  float acc[14] = {};
  for (int c = 0; c < 128; ++c) {
    const float a = buf[lane*129 + c];
    const float* __restrict__ wr = W + W1_OMT + c*108 + obase;
    #pragma unroll
    for (int oi = 0; oi < 14; ++oi) acc[oi] += a * wr[oi];  // oi=13 on wave7 reads next row start (valid mem), discarded
  }
  __syncthreads();
  #pragma unroll
  for (int oi = 0; oi < 14; ++oi)
    if (oi < cnt) buf[lane*129 + obase + oi] = acc[oi] + W[W1_OMB + obase + oi];
  __syncthreads();
  for (int it = 0; it < 14; ++it) {
    int idx = it*512 + tid;          // 6912 = 64*108
    if (idx < 6912) {
      int p = idx / 108, o = idx % 108;
      om[(long)(pbase+p)*108 + o] = buf[p*129 + o];
    }
  }
}

// ---- 3. deformable bilinear sampling (float4 x2, 16 px/block, 8 ch/thread) -> s [P][128]
__global__ __launch_bounds__(256) void k_samp8(const float* __restrict__ v,
                                               const float* __restrict__ om,
                                               float* __restrict__ sout) {
  const int tid = threadIdx.x;
  const long pb = (long)blockIdx.x * 16;
  const int b = (int)(pb / HWn);
  __shared__ float oml[1728];          // om for 16 px
  for (int i = tid; i < 1728; i += 256) oml[i] = om[pb*108 + i];
  __syncthreads();
  const int p16 = tid >> 4, slot = tid & 15;
  const int g = slot >> 2, c = g*32 + (slot & 3)*8;
  const long p = pb + p16;
  const int rem = (int)(p % HWn), h = rem / WW, w = rem % WW;
  const float* vb = v + (long)b*HWn*128;
  const float* op = &oml[p16*108 + g*27];
  float4 a0 = make_float4(0.f,0.f,0.f,0.f), a1 = make_float4(0.f,0.f,0.f,0.f);
  #pragma unroll
  for (int k = 0; k < 9; ++k) {
    const float offx = op[k*3+0], offy = op[k*3+1], m = op[k*3+2];
    const float px = (float)(w + (k % 3)) + offx;   // padded coords, Wp=162
    const float py = (float)(h + (k / 3)) + offy;
    const float x0f = floorf(px), y0f = floorf(py);
    const float tx = px - x0f, ty = py - y0f;
    const int x0 = (int)x0f, y0 = (int)y0f;
    #pragma unroll
    for (int dy = 0; dy < 2; ++dy)
      #pragma unroll
      for (int dx = 0; dx < 2; ++dx) {
        const int xi = x0 + dx, yi = y0 + dy;
        if (xi >= 1 && xi <= WW && yi >= 1 && yi <= HH) {
          const float wq = (dx ? tx : 1.f - tx) * (dy ? ty : 1.f - ty) * m;
          const float* __restrict__ vr = &vb[(long)((yi-1)*WW + (xi-1))*128 + c];
          const float4 v0 = *(const float4*)vr;
          const float4 v1 = *(const float4*)(vr + 4);
          a0.x += wq*v0.x; a0.y += wq*v0.y; a0.z += wq*v0.z; a0.w += wq*v0.w;
          a1.x += wq*v1.x; a1.y += wq*v1.y; a1.z += wq*v1.z; a1.w += wq*v1.w;
        }
      }
  }
  *(float4*)&sout[p*128 + c]     = a0;
  *(float4*)&sout[p*128 + c + 4] = a1;
}

// ---- 4. outp (128->128) + SimpleGate -> f [64][PN] (CHANNEL-MAJOR out)  [8 waves]
__global__ __launch_bounds__(512, 6) void k_outp(const float* __restrict__ s,
                                                 const float* __restrict__ wT,
                                                 const float* __restrict__ bias,
                                                 float* __restrict__ f) {
  const int tid = threadIdx.x, lane = tid & 63;
  const int pbase = blockIdx.x * PPB;
  __shared__ float buf[8256];
  for (int it = 0; it < 4; ++it) {
    int idx = it*512 + tid;     // 2048 f4
    int p = idx >> 5, c4 = idx & 31;
    float4 v = *(const float4*)&s[(long)(pbase+p)*128 + c4*4];
    float* d = &buf[p*129 + c4*4];
    d[0]=v.x; d[1]=v.y; d[2]=v.z; d[3]=v.w;
  }
  __syncthreads();
  const int obase = __builtin_amdgcn_readfirstlane((tid >> 6) * 16);
  float acc[16] = {};
  for (int c = 0; c < 128; ++c) {
    const float a = buf[lane*129 + c];
    const float* __restrict__ wr = wT + c*128 + obase;
    #pragma unroll
    for (int oi = 0; oi < 16; ++oi) acc[oi] += a * wr[oi];
  }
  __syncthreads();
  #pragma unroll
  for (int oi = 0; oi < 16; ++oi)
    buf[lane*129 + obase + oi] = acc[oi] + bias[obase + oi];
  __syncthreads();
  // channel-major store: lanes along p (coalesced); LDS read stride 129 (conflict-free)
  for (int it = 0; it < 8; ++it) {
    int idx = it*512 + tid;     // 4096
    int c = idx >> 6, p = idx & 63;
    f[(long)c*PN + pbase + p] = buf[p*129 + c] * buf[p*129 + 64 + c];
  }
}

// ---- 5a. pool: one block per (b, ch) over CM rows -> pooled[256]
__global__ __launch_bounds__(256) void k_pool(const float* __restrict__ fL,
                                              const float* __restrict__ fR,
                                              float* __restrict__ pooled) {
  const int blk = blockIdx.x;                 // b*128 + ch
  const int b = blk >> 7, ch = blk & 127;
  const float* __restrict__ row = ((ch < 64) ? fL : fR) + (long)(ch & 63)*PN + (long)b*HWn;
  const float4* __restrict__ r4 = (const float4*)row;
  float s = 0.f;
  for (int i = threadIdx.x; i < HWn/4; i += 256) {
    float4 t = r4[i]; s += (t.x + t.y) + (t.z + t.w);
  }
  __shared__ float red[256];
  red[threadIdx.x] = s; __syncthreads();
  for (int k = 128; k > 0; k >>= 1) { if (threadIdx.x < k) red[threadIdx.x] += red[threadIdx.x+k]; __syncthreads(); }
  if (threadIdx.x == 0) pooled[blk] = red[0] / (float)HWn;
}

// ---- 5b. pooled -> scale
__global__ __launch_bounds__(256) void k_scale(const float* __restrict__ pooled,
                                               const void* sca_w, const void* sca_b,
                                               float* __restrict__ scale, const int* flagp) {
  const int bf = *flagp;
  const int t = threadIdx.x, b = t >> 7, o = t & 127;
  float acc = ldin(sca_b, o, bf);
  for (int c = 0; c < 128; ++c) acc += pooled[b*128 + c] * ldin(sca_w, o*128 + c, bf);
  scale[b*128 + o] = acc;
}

// ---- 6. conv3 + residual -> y [128][PN] (rows 0-63 = L, 64-127 = R)   grid(800)
__global__ __launch_bounds__(256) void k_c3y(const float* __restrict__ fL,
                                             const float* __restrict__ fR,
                                             const float* __restrict__ scaleP,
                                             const float* __restrict__ W,
                                             const void* x_l, const void* x_r,
                                             float* __restrict__ y, const int* flagp) {
  const int bf = *flagp;
  const int lane = threadIdx.x & 63, wv = threadIdx.x >> 6;
  const int pbase = blockIdx.x * 64;
  const int b = pbase / HWn, rem = pbase % HWn + lane;
  const long p = pbase + lane;
  const int o16 = __builtin_amdgcn_readfirstlane(wv * 16);
  float acc[16] = {};
  #pragma unroll 4
  for (int c = 0; c < 64; ++c) {
    float a = fL[(long)c*PN + p] * scaleP[b*128 + c];
    const float* __restrict__ wr = W + WB_C3T + c*64 + o16;
    #pragma unroll
    for (int oi = 0; oi < 16; ++oi) acc[oi] += a * wr[oi];
  }
  #pragma unroll 4
  for (int c = 64; c < 128; ++c) {
    float a = fR[(long)(c-64)*PN + p] * scaleP[b*128 + c];
    const float* __restrict__ wr = W + WB_C3T + c*64 + o16;
    #pragma unroll
    for (int oi = 0; oi < 16; ++oi) acc[oi] += a * wr[oi];
  }
  #pragma unroll
  for (int oi = 0; oi < 16; ++oi) {
    const int o = o16 + oi;
    const float x3b = (acc[oi] + W[WB_C3B+o]) * W[WB_BETA+o];
    y[(long)o*PN + p]      = ldin(x_l, (long)(b*C0+o)*HWn + rem, bf) + x3b;
    y[(long)(64+o)*PN + p] = ldin(x_r, (long)(b*C0+o)*HWn + rem, bf) + x3b;
  }
}

// ---- 7. LN(128) + conv4 + SG + conv5 + residual -> dout NCHW  [8 waves, sg in LDS]
__global__ __launch_bounds__(512) void k_ln2c45(const float* __restrict__ y,
                                                const float* __restrict__ W,
                                                void* dout, const int* flagp) {
  const int bf = *flagp;
  const int tid = threadIdx.x, lane = tid & 63, wv = tid >> 6;
  const int pbase = blockIdx.x * 64;
  const int b = pbase / HWn, rem = pbase % HWn + lane;
  const long p = pbase + lane;
  __shared__ float sgs[64*65];   // [px][65] SimpleGate output, stride-65 conflict-free
  const int gb = __builtin_amdgcn_readfirstlane(wv * 8);
  float s = 0.f, s2 = 0.f;
  for (int c = 0; c < 128; ++c) {
    float a = y[(long)c*PN + p];
    s += a; s2 += a*a;
  }
  const float mean = s * (1.f/128.f);
  const float rstd = rsqrtf(s2*(1.f/128.f) - mean*mean + 1e-5f);
  float accL[8] = {}, accH[8] = {};
  #pragma unroll 4
  for (int c = 0; c < 128; ++c) {
    float a = y[(long)c*PN + p];
    const float* __restrict__ wrL = W + WB_W4T + c*128 + gb;
    const float* __restrict__ wrH = wrL + 64;
    #pragma unroll
    for (int oi = 0; oi < 8; ++oi) { accL[oi] += a*wrL[oi]; accH[oi] += a*wrH[oi]; }
  }
  #pragma unroll
  for (int oi = 0; oi < 8; ++oi) {
    float tl = rstd*(accL[oi] - mean*W[WB_RS4+gb+oi])    + W[WB_B4+gb+oi];
    float th = rstd*(accH[oi] - mean*W[WB_RS4+64+gb+oi]) + W[WB_B4+64+gb+oi];
    sgs[lane*65 + gb + oi] = tl * th;
  }
  __syncthreads();
  // conv5 (64->64, gamma folded): wave wv computes outputs gb..gb+7
  float acc5[8] = {};
  #pragma unroll 4
  for (int c = 0; c < 64; ++c) {
    const float a = sgs[lane*65 + c];
    const float* __restrict__ wr = W + WB_W5T + c*64 + gb;
    #pragma unroll
    for (int oi = 0; oi < 8; ++oi) acc5[oi] += a * wr[oi];
  }
  #pragma unroll
  for (int oi = 0; oi < 8; ++oi) {
    const int o = gb + oi;
    const float z = acc5[oi] + W[WB_B5G+o];
    const float outL = y[(long)o*PN + p] + z;
    const float outR = y[(long)(64+o)*PN + p] + z;
    stout(dout, (long)(b*C0+o)*HWn + rem, outL, bf);
    stout(dout, (long)BN*C0*HWn + (long)(b*C0+o)*HWn + rem, outR, bf);
  }
}

extern "C" void kernel_launch(void* const* d_in, const int* in_sizes, int n_in,
                              void* d_out, int out_size, void* d_ws, size_t ws_size,
                              hipStream_t stream) {
  const void* x_l    = d_in[0];
  const void* x_r    = d_in[1];
  const void* ln1_g  = d_in[2];
  const void* pw1_w  = d_in[3];
  const void* pw1_b  = d_in[4];
  const void* val_w  = d_in[5];
  const void* val_b  = d_in[6];
  const void* dwc_w  = d_in[7];
  const void* dwc_b  = d_in[8];
  const void* om_w   = d_in[9];
  const void* om_b   = d_in[10];
  const void* outp_w = d_in[11];
  const void* outp_b = d_in[12];
  const void* sca_w  = d_in[13];
  const void* sca_b  = d_in[14];
  const void* conv3_w = d_in[15];
  const void* conv3_b = d_in[16];
  const void* norm2_g = d_in[17];
  const void* conv4_w = d_in[18];
  const void* conv4_b = d_in[19];
  const void* conv5_w = d_in[20];
  const void* conv5_b = d_in[21];
  const void* beta   = d_in[22];
  const void* gamma  = d_in[23];

  int* flag  = (int*)d_ws;
  float* wsf = (float*)((char*)d_ws + 1024);
  // Regions: A = h1/s (PM) -> y (CM); Bv = v (PM) -> pooled/scale/WB; Cm = om (PM);
  //          fL/fR = f (CM); W1 in fR until side-1 k_outp; WB in dead v.
  float* A  = wsf;
  float* Bv = wsf + S128;
  float* Cm = wsf + 2*S128;
  float* fL = wsf + 2*S128 + S108;
  float* fR = fL + S64v;
  float* W1 = fR;
  float* WB = Bv + 26000;
  float* pooled = Bv;                    // 256 floats
  float* scaleP = Bv + 512;              // 256 floats (disjoint from WB at +26000)

  hipLaunchKernelGGL(k_conv1, dim3(64), dim3(256), 0, stream,
                     pw1_w, ln1_g, pw1_b, val_w, val_b, dwc_w, dwc_b,
                     om_w, om_b, outp_w, outp_b, W1, flag);

  // side 0 (pixel-major pipeline)
  hipLaunchKernelGGL(k_lnpw1v, dim3(NB),    dim3(512), 0, stream, x_l, W1, A, Bv, flag);
  hipLaunchKernelGGL(k_dwom4,  dim3(NB),    dim3(512), 0, stream, A, W1, Cm);
  hipLaunchKernelGGL(k_samp8,  dim3(PN/16), dim3(256), 0, stream, Bv, Cm, A);
  hipLaunchKernelGGL(k_outp,   dim3(NB),    dim3(512), 0, stream, A, W1 + W1_OUTT, W1 + W1_OUTB, fL);
  // side 1
  hipLaunchKernelGGL(k_lnpw1v, dim3(NB),    dim3(512), 0, stream, x_r, W1, A, Bv, flag);
  hipLaunchKernelGGL(k_dwom4,  dim3(NB),    dim3(512), 0, stream, A, W1, Cm);
  hipLaunchKernelGGL(k_samp8,  dim3(PN/16), dim3(256), 0, stream, Bv, Cm, A);
  hipLaunchKernelGGL(k_conv2,  dim3(64),    dim3(256), 0, stream,
                     outp_w, outp_b, conv3_w, conv3_b, beta, norm2_g,
                     conv4_w, conv4_b, conv5_w, conv5_b, gamma, WB, flag);
  hipLaunchKernelGGL(k_outp,   dim3(NB),    dim3(512), 0, stream, A, WB + WB_OUTT, WB + WB_OUTB, fR);

  // phase 2 (channel-major)
  hipLaunchKernelGGL(k_pool,   dim3(256),   dim3(256), 0, stream, fL, fR, pooled);
  hipLaunchKernelGGL(k_scale,  dim3(1),     dim3(256), 0, stream, pooled, sca_w, sca_b, scaleP, flag);
  hipLaunchKernelGGL(k_c3y,    dim3(800),   dim3(256), 0, stream, fL, fR, scaleP, WB,
                     x_l, x_r, A, flag);
  hipLaunchKernelGGL(k_ln2c45, dim3(800),   dim3(512), 0, stream, A, WB, d_out, flag);
}

// Round 10
// 582.336 us; speedup vs baseline: 1.0526x; 1.0526x over previous
//
#include <hip/hip_runtime.h>
#include <hip/hip_bf16.h>

#define BN 2
#define C0 64
#define HH 160
#define WW 160
#define HWn (HH*WW)          // 25600
#define PN (BN*HWn)          // 51200
#define DWCH 128
#define OMC 108
#define PPB 64
#define NB (PN/PPB)          // 800

#define S128 ((long)PN*128)
#define S108 ((long)PN*108)
#define S64v ((long)PN*64)

// ---- phase-1 weight pack (lives in fR region; fR written only by side-1 k_outp)
#define W1_PW1T   0        // [64c][128o] pw1_w * ln1_g[c], transposed
#define W1_RS1    8192     // [128] rowsum of pw1T over c
#define W1_PB1    8320     // [128]
#define W1_VALT   8448     // [128c][128o]
#define W1_VB     24832    // [128]
#define W1_DWC    24960    // [1152]
#define W1_DWB    26112    // [128]
#define W1_OMT    26240    // [128c][108o]
#define W1_OMB    40064    // [108]
#define W1_OUTT   40172    // [128c][128o]
#define W1_OUTB   56556    // [128]
// ---- phase-2 weight pack (Bv+26000; v dead after side-1 k_samp8b)
#define WB_OUTT   0        // [128c][128o]
#define WB_OUTB   16384
#define WB_C3T    16512    // [128c][64o]
#define WB_C3B    24704
#define WB_BETA   24768
#define WB_W4T    24832    // [128c][128o] conv4_w * norm2_g[c], transposed
#define WB_RS4    41216
#define WB_B4     41344
#define WB_W5T    41472    // [64c][64o] conv5_w * gamma[o], transposed
#define WB_B5G    45568    // [64] conv5_b * gamma

__device__ __forceinline__ float ldin(const void* p, long i, int bf) {
  return bf ? __bfloat162float(((const __hip_bfloat16*)p)[i])
            : ((const float*)p)[i];
}
__device__ __forceinline__ void stout(void* p, long i, float v, int bf) {
  if (bf) ((__hip_bfloat16*)p)[i] = __float2bfloat16(v);
  else    ((float*)p)[i] = v;
}

// ---- weight conversion, phase 1 (into fR region); also publishes dtype flag
__global__ void k_conv1(const void* pw1_w, const void* ln1_g, const void* pw1_b,
                        const void* val_w, const void* val_b,
                        const void* dwc_w, const void* dwc_b,
                        const void* om_w, const void* om_b,
                        const void* outp_w, const void* outp_b,
                        float* __restrict__ W, int* flag) {
  const int bf = (*(const unsigned*)ln1_g == 0x3F800000u) ? 0 : 1;
  if (blockIdx.x == 0 && threadIdx.x == 0) *flag = bf;
  const int g0 = blockIdx.x*256 + threadIdx.x, GS = gridDim.x*256;
  for (int i = g0; i < 8192; i += GS) { int c = i>>7, o = i&127;
    W[W1_PW1T + i] = ldin(pw1_w, o*64 + c, bf) * ldin(ln1_g, c, bf); }
  for (int o = g0; o < 128; o += GS) { float s = 0.f;
    for (int c = 0; c < 64; ++c) s += ldin(pw1_w, o*64+c, bf) * ldin(ln1_g, c, bf);
    W[W1_RS1 + o] = s; W[W1_PB1 + o] = ldin(pw1_b, o, bf); }
  for (int i = g0; i < 16384; i += GS) { int c = i>>7, o = i&127;
    W[W1_VALT + i] = ldin(val_w, o*128 + c, bf); }
  for (int i = g0; i < 128; i += GS) W[W1_VB + i] = ldin(val_b, i, bf);
  for (int i = g0; i < 1152; i += GS) W[W1_DWC + i] = ldin(dwc_w, i, bf);
  for (int i = g0; i < 128; i += GS) W[W1_DWB + i] = ldin(dwc_b, i, bf);
  for (int i = g0; i < 13824; i += GS) { int c = i/108, o = i%108;
    W[W1_OMT + i] = ldin(om_w, o*128 + c, bf); }
  for (int i = g0; i < 108; i += GS) W[W1_OMB + i] = ldin(om_b, i, bf);
  for (int i = g0; i < 16384; i += GS) { int c = i>>7, o = i&127;
    W[W1_OUTT + i] = ldin(outp_w, o*128 + c, bf); }
  for (int i = g0; i < 128; i += GS) W[W1_OUTB + i] = ldin(outp_b, i, bf);
}

// ---- weight conversion, phase 2 (into Bv+26000)
__global__ void k_conv2(const void* outp_w, const void* outp_b,
                        const void* conv3_w, const void* conv3_b, const void* beta,
                        const void* norm2_g, const void* conv4_w, const void* conv4_b,
                        const void* conv5_w, const void* conv5_b, const void* gamma,
                        float* __restrict__ W, const int* flagp) {
  const int bf = *flagp;
  const int g0 = blockIdx.x*256 + threadIdx.x, GS = gridDim.x*256;
  for (int i = g0; i < 16384; i += GS) { int c = i>>7, o = i&127;
    W[WB_OUTT + i] = ldin(outp_w, o*128 + c, bf); }
  for (int i = g0; i < 128; i += GS) W[WB_OUTB + i] = ldin(outp_b, i, bf);
  for (int i = g0; i < 8192; i += GS) { int c = i>>6, o = i&63;
    W[WB_C3T + i] = ldin(conv3_w, o*128 + c, bf); }
  for (int i = g0; i < 64; i += GS) { W[WB_C3B + i] = ldin(conv3_b, i, bf);
    W[WB_BETA + i] = ldin(beta, i, bf); }
  for (int i = g0; i < 16384; i += GS) { int c = i>>7, o = i&127;
    W[WB_W4T + i] = ldin(conv4_w, o*128 + c, bf) * ldin(norm2_g, c, bf); }
  for (int o = g0; o < 128; o += GS) { float s = 0.f;
    for (int c = 0; c < 128; ++c) s += ldin(conv4_w, o*128+c, bf) * ldin(norm2_g, c, bf);
    W[WB_RS4 + o] = s; W[WB_B4 + o] = ldin(conv4_b, o, bf); }
  for (int i = g0; i < 4096; i += GS) { int c = i>>6, o = i&63;
    W[WB_W5T + i] = ldin(conv5_w, o*64 + c, bf) * ldin(gamma, o, bf); }
  for (int i = g0; i < 64; i += GS)
    W[WB_B5G + i] = ldin(conv5_b, i, bf) * ldin(gamma, i, bf);
}

// ---- 1. LN(64) + pw1 + val -> h1, v  [8 waves; stats folded into pw1 loop]
__global__ __launch_bounds__(512, 6) void k_lnpw1v(const void* x, const float* __restrict__ W,
                                                   float* __restrict__ h1, float* __restrict__ vout,
                                                   const int* flagp) {
  const int bf = *flagp;
  const int tid = threadIdx.x, lane = tid & 63;
  const int pbase = blockIdx.x * PPB;
  const int b = pbase / HWn, rem0 = pbase % HWn;
  __shared__ float buf[8256];   // raw x (stride 65) -> h1 (stride 129) -> v (stride 129)
  for (int it = 0; it < 8; ++it) {
    int idx = it*512 + tid;     // 4096 = 64c x 64p
    int c = idx >> 6, p = idx & 63;
    buf[p*65 + c] = ldin(x, (long)(b*C0 + c)*HWn + rem0 + p, bf);
  }
  __syncthreads();
  const int obase = __builtin_amdgcn_readfirstlane((tid >> 6) * 16);
  float s = 0.f, s2 = 0.f;
  float acc[16] = {};
  for (int c = 0; c < 64; ++c) {
    const float a = buf[lane*65 + c];
    s += a; s2 += a*a;
    const float* __restrict__ wr = W + W1_PW1T + c*128 + obase;
    #pragma unroll
    for (int oi = 0; oi < 16; ++oi) acc[oi] += a * wr[oi];
  }
  const float mean = s * (1.f/64.f);
  const float rstd = rsqrtf(s2 * (1.f/64.f) - mean*mean + 1e-5f);
  __syncthreads();   // all stride-65 reads done
  #pragma unroll
  for (int oi = 0; oi < 16; ++oi)
    buf[lane*129 + obase + oi] =
      rstd*(acc[oi] - mean*W[W1_RS1 + obase + oi]) + W[W1_PB1 + obase + oi];
  __syncthreads();
  for (int it = 0; it < 4; ++it) {
    int idx = it*512 + tid;     // 2048 f4
    int p = idx >> 5, c4 = idx & 31;
    const float* sp = &buf[p*129 + c4*4];
    *(float4*)&h1[(long)(pbase+p)*128 + c4*4] = make_float4(sp[0],sp[1],sp[2],sp[3]);
  }
  float acc2[16] = {};
  for (int c = 0; c < 128; ++c) {
    const float a = buf[lane*129 + c];
    const float* __restrict__ wr = W + W1_VALT + c*128 + obase;
    #pragma unroll
    for (int oi = 0; oi < 16; ++oi) acc2[oi] += a * wr[oi];
  }
  __syncthreads();
  #pragma unroll
  for (int oi = 0; oi < 16; ++oi)
    buf[lane*129 + obase + oi] = acc2[oi] + W[W1_VB + obase + oi];
  __syncthreads();
  for (int it = 0; it < 4; ++it) {
    int idx = it*512 + tid;
    int p = idx >> 5, c4 = idx & 31;
    const float* sp = &buf[p*129 + c4*4];
    *(float4*)&vout[(long)(pbase+p)*128 + c4*4] = make_float4(sp[0],sp[1],sp[2],sp[3]);
  }
}

// ---- 2. depthwise 3x3 (8 ch/thread staging) + om head (128->108)  [8 waves]
__global__ __launch_bounds__(512, 6) void k_dwom4(const float* __restrict__ h1,
                                                  const float* __restrict__ W,
                                                  float* __restrict__ om) {
  const int tid = threadIdx.x, lane = tid & 63;
  const int pbase = blockIdx.x * PPB;
  const int b = pbase / HWn, rem0 = pbase % HWn;
  __shared__ float buf[8256];
  __shared__ float dww[1280];
  for (int i = tid; i < 1280; i += 512)
    dww[i] = (i < 1152) ? W[W1_DWC + i] : W[W1_DWB + i - 1152];
  __syncthreads();
  for (int it = 0; it < 2; ++it) {
    int idx = it*512 + tid;          // 1024 = 64 px x 16 slots(8ch)
    int p = idx >> 4, c = (idx & 15)*8;
    int rem = rem0 + p, h = rem / WW, w2 = rem % WW;
    float4 a0 = *(const float4*)&dww[1152 + c];
    float4 a1 = *(const float4*)&dww[1152 + c + 4];
    #pragma unroll
    for (int ky = 0; ky < 3; ++ky) {
      int hh = h + ky - 1;
      if (hh < 0 || hh >= HH) continue;
      #pragma unroll
      for (int kx = 0; kx < 3; ++kx) {
        int ww2 = w2 + kx - 1;
        if (ww2 < 0 || ww2 >= WW) continue;
        const float* __restrict__ hr = &h1[(long)(b*HWn + hh*WW + ww2)*128 + c];
        float4 h0 = *(const float4*)hr, h4 = *(const float4*)(hr + 4);
        const float* __restrict__ wv = &dww[(ky*3+kx)*128 + c];
        float4 w0 = *(const float4*)wv, w4 = *(const float4*)(wv + 4);
        a0.x += h0.x*w0.x; a0.y += h0.y*w0.y; a0.z += h0.z*w0.z; a0.w += h0.w*w0.w;
        a1.x += h4.x*w4.x; a1.y += h4.y*w4.y; a1.z += h4.z*w4.z; a1.w += h4.w*w4.w;
      }
    }
    float* d = &buf[p*129 + c];
    d[0]=a0.x; d[1]=a0.y; d[2]=a0.z; d[3]=a0.w;
    d[4]=a1.x; d[5]=a1.y; d[6]=a1.z; d[7]=a1.w;
  }
  __syncthreads();
  const int wv = tid >> 6;
  const int cnt = (wv < 4) ? 14 : 13;
  const int obase = __builtin_amdgcn_readfirstlane((wv < 4) ? wv*14 : 56 + (wv-4)*13);
  float acc[14] = {};
  for (int c = 0; c < 128; ++c) {
    const float a = buf[lane*129 + c];
    const float* __restrict__ wr = W + W1_OMT + c*108 + obase;
    #pragma unroll
    for (int oi = 0; oi < 14; ++oi) acc[oi] += a * wr[oi];  // oi=13 on wave7 reads next row start (valid mem), discarded
  }
  __syncthreads();
  #pragma unroll
  for (int oi = 0; oi < 14; ++oi)
    if (oi < cnt) buf[lane*129 + obase + oi] = acc[oi] + W[W1_OMB + obase + oi];
  __syncthreads();
  for (int it = 0; it < 14; ++it) {
    int idx = it*512 + tid;          // 6912 = 64*108
    if (idx < 6912) {
      int p = idx / 108, o = idx % 108;
      om[(long)(pbase+p)*108 + o] = buf[p*129 + o];
    }
  }
}

// ---- 3. deformable sampling: coord precompute in LDS + 8 ch/thread -> s [P][128]
__global__ __launch_bounds__(256) void k_samp8b(const float* __restrict__ v,
                                                const float* __restrict__ om,
                                                float* __restrict__ sout) {
  const int tid = threadIdx.x;
  const long pb = (long)blockIdx.x * 16;
  const int b = (int)(pb / HWn);
  __shared__ float pre[4608];   // 16px x 4g x 9k x {w0..w3, addr0..addr3}
  for (int idx = tid; idx < 576; idx += 256) {
    const int px = idx / 36, rest = idx % 36, g = rest / 9, k = rest % 9;
    const long p = pb + px;
    const int rem = (int)(p % HWn), h = rem / WW, w = rem % WW;
    const float offx = om[p*108 + g*27 + k*3 + 0];
    const float offy = om[p*108 + g*27 + k*3 + 1];
    const float m    = om[p*108 + g*27 + k*3 + 2];
    const float pxf = (float)(w + (k % 3)) + offx;   // padded coords, Wp=162
    const float pyf = (float)(h + (k / 3)) + offy;
    const float x0f = floorf(pxf), y0f = floorf(pyf);
    const float tx = pxf - x0f, ty = pyf - y0f;
    const int x0 = (int)x0f, y0 = (int)y0f;
    float wv[4]; int av[4];
    #pragma unroll
    for (int dy = 0; dy < 2; ++dy)
      #pragma unroll
      for (int dx = 0; dx < 2; ++dx) {
        const int xi = x0 + dx, yi = y0 + dy;
        const bool ok = (xi >= 1 && xi <= WW && yi >= 1 && yi <= HH);
        const float wq = ok ? (dx ? tx : 1.f - tx) * (dy ? ty : 1.f - ty) * m : 0.f;
        const int xc = min(max(xi, 1), WW), yc = min(max(yi, 1), HH);
        wv[dy*2+dx] = wq; av[dy*2+dx] = (yc-1)*WW + (xc-1);
      }
    *(float4*)&pre[idx*8]     = make_float4(wv[0], wv[1], wv[2], wv[3]);
    *(float4*)&pre[idx*8 + 4] = make_float4(__int_as_float(av[0]), __int_as_float(av[1]),
                                            __int_as_float(av[2]), __int_as_float(av[3]));
  }
  __syncthreads();
  const int p16 = tid >> 4, slot = tid & 15;
  const int g = slot >> 2, c = g*32 + (slot & 3)*8;
  const long p = pb + p16;
  const float* __restrict__ vb = v + (long)b*HWn*128;
  const int base0 = ((p16*4 + g)*9)*8;
  float4 a0 = make_float4(0.f,0.f,0.f,0.f), a1 = make_float4(0.f,0.f,0.f,0.f);
  #pragma unroll
  for (int k = 0; k < 9; ++k) {
    const float4 wq4 = *(const float4*)&pre[base0 + k*8];
    const float4 ad4 = *(const float4*)&pre[base0 + k*8 + 4];
    #pragma unroll
    for (int j = 0; j < 4; ++j) {
      const float wq = (j==0)?wq4.x:(j==1)?wq4.y:(j==2)?wq4.z:wq4.w;
      const int pix = __float_as_int((j==0)?ad4.x:(j==1)?ad4.y:(j==2)?ad4.z:ad4.w);
      const float* __restrict__ vr = vb + (long)pix*128 + c;
      const float4 v0 = *(const float4*)vr;
      const float4 v1 = *(const float4*)(vr + 4);
      a0.x += wq*v0.x; a0.y += wq*v0.y; a0.z += wq*v0.z; a0.w += wq*v0.w;
      a1.x += wq*v1.x; a1.y += wq*v1.y; a1.z += wq*v1.z; a1.w += wq*v1.w;
    }
  }
  *(float4*)&sout[p*128 + c]     = a0;
  *(float4*)&sout[p*128 + c + 4] = a1;
}

// ---- 4. outp + SimpleGate -> f [64][PN] (CM), gate pairs in registers  [8 waves]
__global__ __launch_bounds__(512, 6) void k_outp(const float* __restrict__ s,
                                                 const float* __restrict__ wT,
                                                 const float* __restrict__ bias,
                                                 float* __restrict__ f) {
  const int tid = threadIdx.x, lane = tid & 63;
  const int pbase = blockIdx.x * PPB;
  __shared__ float buf[8256];
  for (int it = 0; it < 4; ++it) {
    int idx = it*512 + tid;     // 2048 f4
    int p = idx >> 5, c4 = idx & 31;
    float4 v = *(const float4*)&s[(long)(pbase+p)*128 + c4*4];
    float* d = &buf[p*129 + c4*4];
    d[0]=v.x; d[1]=v.y; d[2]=v.z; d[3]=v.w;
  }
  __syncthreads();
  const int gb = __builtin_amdgcn_readfirstlane((tid >> 6) * 8);
  float accL[8] = {}, accH[8] = {};
  for (int c = 0; c < 128; ++c) {
    const float a = buf[lane*129 + c];
    const float* __restrict__ wrL = wT + c*128 + gb;
    const float* __restrict__ wrH = wrL + 64;
    #pragma unroll
    for (int oi = 0; oi < 8; ++oi) { accL[oi] += a*wrL[oi]; accH[oi] += a*wrH[oi]; }
  }
  #pragma unroll
  for (int oi = 0; oi < 8; ++oi)
    f[(long)(gb+oi)*PN + pbase + lane] =
      (accL[oi] + bias[gb+oi]) * (accH[oi] + bias[64+gb+oi]);
}

// ---- 5a. pool: one block per (b, ch) over CM rows -> pooled[256]
__global__ __launch_bounds__(256) void k_pool(const float* __restrict__ fL,
                                              const float* __restrict__ fR,
                                              float* __restrict__ pooled) {
  const int blk = blockIdx.x;                 // b*128 + ch
  const int b = blk >> 7, ch = blk & 127;
  const float* __restrict__ row = ((ch < 64) ? fL : fR) + (long)(ch & 63)*PN + (long)b*HWn;
  const float4* __restrict__ r4 = (const float4*)row;
  float s = 0.f;
  for (int i = threadIdx.x; i < HWn/4; i += 256) {
    float4 t = r4[i]; s += (t.x + t.y) + (t.z + t.w);
  }
  __shared__ float red[256];
  red[threadIdx.x] = s; __syncthreads();
  for (int k = 128; k > 0; k >>= 1) { if (threadIdx.x < k) red[threadIdx.x] += red[threadIdx.x+k]; __syncthreads(); }
  if (threadIdx.x == 0) pooled[blk] = red[0] / (float)HWn;
}

// ---- 5b. pooled -> scale
__global__ __launch_bounds__(256) void k_scale(const float* __restrict__ pooled,
                                               const void* sca_w, const void* sca_b,
                                               float* __restrict__ scale, const int* flagp) {
  const int bf = *flagp;
  const int t = threadIdx.x, b = t >> 7, o = t & 127;
  float acc = ldin(sca_b, o, bf);
  for (int c = 0; c < 128; ++c) acc += pooled[b*128 + c] * ldin(sca_w, o*128 + c, bf);
  scale[b*128 + o] = acc;
}

// ---- 6. conv3 + residual -> y [128][PN] (rows 0-63 = L, 64-127 = R)   grid(800)
__global__ __launch_bounds__(256) void k_c3y(const float* __restrict__ fL,
                                             const float* __restrict__ fR,
                                             const float* __restrict__ scaleP,
                                             const float* __restrict__ W,
                                             const void* x_l, const void* x_r,
                                             float* __restrict__ y, const int* flagp) {
  const int bf = *flagp;
  const int lane = threadIdx.x & 63, wv = threadIdx.x >> 6;
  const int pbase = blockIdx.x * 64;
  const int b = pbase / HWn, rem = pbase % HWn + lane;
  const long p = pbase + lane;
  const int o16 = __builtin_amdgcn_readfirstlane(wv * 16);
  float acc[16] = {};
  #pragma unroll 4
  for (int c = 0; c < 64; ++c) {
    float a = fL[(long)c*PN + p] * scaleP[b*128 + c];
    const float* __restrict__ wr = W + WB_C3T + c*64 + o16;
    #pragma unroll
    for (int oi = 0; oi < 16; ++oi) acc[oi] += a * wr[oi];
  }
  #pragma unroll 4
  for (int c = 64; c < 128; ++c) {
    float a = fR[(long)(c-64)*PN + p] * scaleP[b*128 + c];
    const float* __restrict__ wr = W + WB_C3T + c*64 + o16;
    #pragma unroll
    for (int oi = 0; oi < 16; ++oi) acc[oi] += a * wr[oi];
  }
  #pragma unroll
  for (int oi = 0; oi < 16; ++oi) {
    const int o = o16 + oi;
    const float x3b = (acc[oi] + W[WB_C3B+o]) * W[WB_BETA+o];
    y[(long)o*PN + p]      = ldin(x_l, (long)(b*C0+o)*HWn + rem, bf) + x3b;
    y[(long)(64+o)*PN + p] = ldin(x_r, (long)(b*C0+o)*HWn + rem, bf) + x3b;
  }
}

// ---- 7. LN(128) + conv4 + SG + conv5 + residual -> dout  [single y pass]
__global__ __launch_bounds__(512) void k_ln2c45(const float* __restrict__ y,
                                                const float* __restrict__ W,
                                                void* dout, const int* flagp) {
  const int bf = *flagp;
  const int tid = threadIdx.x, lane = tid & 63, wv = tid >> 6;
  const int pbase = blockIdx.x * 64;
  const int b = pbase / HWn, rem = pbase % HWn + lane;
  const long p = pbase + lane;
  __shared__ float sgs[64*65];   // [px][65] SimpleGate output, stride-65 conflict-free
  const int gb = __builtin_amdgcn_readfirstlane(wv * 8);
  float s = 0.f, s2 = 0.f;
  float accL[8] = {}, accH[8] = {};
  #pragma unroll 4
  for (int c = 0; c < 128; ++c) {
    const float a = y[(long)c*PN + p];
    s += a; s2 += a*a;
    const float* __restrict__ wrL = W + WB_W4T + c*128 + gb;
    const float* __restrict__ wrH = wrL + 64;
    #pragma unroll
    for (int oi = 0; oi < 8; ++oi) { accL[oi] += a*wrL[oi]; accH[oi] += a*wrH[oi]; }
  }
  const float mean = s * (1.f/128.f);
  const float rstd = rsqrtf(s2*(1.f/128.f) - mean*mean + 1e-5f);
  #pragma unroll
  for (int oi = 0; oi < 8; ++oi) {
    float tl = rstd*(accL[oi] - mean*W[WB_RS4+gb+oi])    + W[WB_B4+gb+oi];
    float th = rstd*(accH[oi] - mean*W[WB_RS4+64+gb+oi]) + W[WB_B4+64+gb+oi];
    sgs[lane*65 + gb + oi] = tl * th;
  }
  __syncthreads();
  // conv5 (64->64, gamma folded): wave wv computes outputs gb..gb+7
  float acc5[8] = {};
  #pragma unroll 4
  for (int c = 0; c < 64; ++c) {
    const float a = sgs[lane*65 + c];
    const float* __restrict__ wr = W + WB_W5T + c*64 + gb;
    #pragma unroll
    for (int oi = 0; oi < 8; ++oi) acc5[oi] += a * wr[oi];
  }
  #pragma unroll
  for (int oi = 0; oi < 8; ++oi) {
    const int o = gb + oi;
    const float z = acc5[oi] + W[WB_B5G+o];
    const float outL = y[(long)o*PN + p] + z;
    const float outR = y[(long)(64+o)*PN + p] + z;
    stout(dout, (long)(b*C0+o)*HWn + rem, outL, bf);
    stout(dout, (long)BN*C0*HWn + (long)(b*C0+o)*HWn + rem, outR, bf);
  }
}

extern "C" void kernel_launch(void* const* d_in, const int* in_sizes, int n_in,
                              void* d_out, int out_size, void* d_ws, size_t ws_size,
                              hipStream_t stream) {
  const void* x_l    = d_in[0];
  const void* x_r    = d_in[1];
  const void* ln1_g  = d_in[2];
  const void* pw1_w  = d_in[3];
  const void* pw1_b  = d_in[4];
  const void* val_w  = d_in[5];
  const void* val_b  = d_in[6];
  const void* dwc_w  = d_in[7];
  const void* dwc_b  = d_in[8];
  const void* om_w   = d_in[9];
  const void* om_b   = d_in[10];
  const void* outp_w = d_in[11];
  const void* outp_b = d_in[12];
  const void* sca_w  = d_in[13];
  const void* sca_b  = d_in[14];
  const void* conv3_w = d_in[15];
  const void* conv3_b = d_in[16];
  const void* norm2_g = d_in[17];
  const void* conv4_w = d_in[18];
  const void* conv4_b = d_in[19];
  const void* conv5_w = d_in[20];
  const void* conv5_b = d_in[21];
  const void* beta   = d_in[22];
  const void* gamma  = d_in[23];

  int* flag  = (int*)d_ws;
  float* wsf = (float*)((char*)d_ws + 1024);
  // Regions: A = h1/s (PM) -> y (CM); Bv = v (PM) -> pooled/scale/WB; Cm = om (PM);
  //          fL/fR = f (CM); W1 in fR until side-1 k_outp; WB in dead v.
  float* A  = wsf;
  float* Bv = wsf + S128;
  float* Cm = wsf + 2*S128;
  float* fL = wsf + 2*S128 + S108;
  float* fR = fL + S64v;
  float* W1 = fR;
  float* WB = Bv + 26000;
  float* pooled = Bv;                    // 256 floats
  float* scaleP = Bv + 512;              // 256 floats (disjoint from WB at +26000)

  hipLaunchKernelGGL(k_conv1, dim3(64), dim3(256), 0, stream,
                     pw1_w, ln1_g, pw1_b, val_w, val_b, dwc_w, dwc_b,
                     om_w, om_b, outp_w, outp_b, W1, flag);

  // side 0 (pixel-major pipeline)
  hipLaunchKernelGGL(k_lnpw1v, dim3(NB),    dim3(512), 0, stream, x_l, W1, A, Bv, flag);
  hipLaunchKernelGGL(k_dwom4,  dim3(NB),    dim3(512), 0, stream, A, W1, Cm);
  hipLaunchKernelGGL(k_samp8b, dim3(PN/16), dim3(256), 0, stream, Bv, Cm, A);
  hipLaunchKernelGGL(k_outp,   dim3(NB),    dim3(512), 0, stream, A, W1 + W1_OUTT, W1 + W1_OUTB, fL);
  // side 1
  hipLaunchKernelGGL(k_lnpw1v, dim3(NB),    dim3(512), 0, stream, x_r, W1, A, Bv, flag);
  hipLaunchKernelGGL(k_dwom4,  dim3(NB),    dim3(512), 0, stream, A, W1, Cm);
  hipLaunchKernelGGL(k_samp8b, dim3(PN/16), dim3(256), 0, stream, Bv, Cm, A);
  hipLaunchKernelGGL(k_conv2,  dim3(64),    dim3(256), 0, stream,
                     outp_w, outp_b, conv3_w, conv3_b, beta, norm2_g,
                     conv4_w, conv4_b, conv5_w, conv5_b, gamma, WB, flag);
  hipLaunchKernelGGL(k_outp,   dim3(NB),    dim3(512), 0, stream, A, WB + WB_OUTT, WB + WB_OUTB, fR);

  // phase 2 (channel-major)
  hipLaunchKernelGGL(k_pool,   dim3(256),   dim3(256), 0, stream, fL, fR, pooled);
  hipLaunchKernelGGL(k_scale,  dim3(1),     dim3(256), 0, stream, pooled, sca_w, sca_b, scaleP, flag);
  hipLaunchKernelGGL(k_c3y,    dim3(800),   dim3(256), 0, stream, fL, fR, scaleP, WB,
                     x_l, x_r, A, flag);
  hipLaunchKernelGGL(k_ln2c45, dim3(800),   dim3(512), 0, stream, A, WB, d_out, flag);
}

// Round 11
// 554.704 us; speedup vs baseline: 1.1051x; 1.0498x over previous
//
#include <hip/hip_runtime.h>
#include <hip/hip_bf16.h>

#define BN 2
#define C0 64
#define HH 160
#define WW 160
#define HWn (HH*WW)          // 25600
#define PN (BN*HWn)          // 51200
#define DWCH 128
#define OMC 108
#define PPB 64
#define NB (PN/PPB)          // 800

#define S128 ((long)PN*128)
#define S108 ((long)PN*108)
#define S64v ((long)PN*64)

// ---- phase-1 weight pack (lives in fR region; fR written only by side-1 k_outp)
#define W1_PW1T   0        // [64c][128o] pw1_w * ln1_g[c], transposed
#define W1_RS1    8192     // [128] rowsum of pw1T over c
#define W1_PB1    8320     // [128]
#define W1_VALT   8448     // [128c][128o]
#define W1_VB     24832    // [128]
#define W1_DWC    24960    // [1152]
#define W1_DWB    26112    // [128]
#define W1_OMT    26240    // [128c][108o]
#define W1_OMB    40064    // [108]
#define W1_OUTT   40172    // [128c][128o]
#define W1_OUTB   56556    // [128]
// ---- phase-2 weight pack (Bv+26000; v dead after side-1 k_samp8b)
#define WB_OUTT   0        // [128c][128o]
#define WB_OUTB   16384
#define WB_C3T    16512    // [128c][64o]
#define WB_C3B    24704
#define WB_BETA   24768
#define WB_W4T    24832    // [128c][128o] conv4_w * norm2_g[c], transposed
#define WB_RS4    41216
#define WB_B4     41344
#define WB_W5T    41472    // [64c][64o] conv5_w * gamma[o], transposed
#define WB_B5G    45568    // [64] conv5_b * gamma

__device__ __forceinline__ float ldin(const void* p, long i, int bf) {
  return bf ? __bfloat162float(((const __hip_bfloat16*)p)[i])
            : ((const float*)p)[i];
}
__device__ __forceinline__ void stout(void* p, long i, float v, int bf) {
  if (bf) ((__hip_bfloat16*)p)[i] = __float2bfloat16(v);
  else    ((float*)p)[i] = v;
}

// ---- weight conversion, phase 1 (into fR region); also publishes dtype flag
__global__ void k_conv1(const void* pw1_w, const void* ln1_g, const void* pw1_b,
                        const void* val_w, const void* val_b,
                        const void* dwc_w, const void* dwc_b,
                        const void* om_w, const void* om_b,
                        const void* outp_w, const void* outp_b,
                        float* __restrict__ W, int* flag) {
  const int bf = (*(const unsigned*)ln1_g == 0x3F800000u) ? 0 : 1;
  if (blockIdx.x == 0 && threadIdx.x == 0) *flag = bf;
  const int g0 = blockIdx.x*256 + threadIdx.x, GS = gridDim.x*256;
  for (int i = g0; i < 8192; i += GS) { int c = i>>7, o = i&127;
    W[W1_PW1T + i] = ldin(pw1_w, o*64 + c, bf) * ldin(ln1_g, c, bf); }
  for (int o = g0; o < 128; o += GS) { float s = 0.f;
    for (int c = 0; c < 64; ++c) s += ldin(pw1_w, o*64+c, bf) * ldin(ln1_g, c, bf);
    W[W1_RS1 + o] = s; W[W1_PB1 + o] = ldin(pw1_b, o, bf); }
  for (int i = g0; i < 16384; i += GS) { int c = i>>7, o = i&127;
    W[W1_VALT + i] = ldin(val_w, o*128 + c, bf); }
  for (int i = g0; i < 128; i += GS) W[W1_VB + i] = ldin(val_b, i, bf);
  for (int i = g0; i < 1152; i += GS) W[W1_DWC + i] = ldin(dwc_w, i, bf);
  for (int i = g0; i < 128; i += GS) W[W1_DWB + i] = ldin(dwc_b, i, bf);
  for (int i = g0; i < 13824; i += GS) { int c = i/108, o = i%108;
    W[W1_OMT + i] = ldin(om_w, o*128 + c, bf); }
  for (int i = g0; i < 108; i += GS) W[W1_OMB + i] = ldin(om_b, i, bf);
  for (int i = g0; i < 16384; i += GS) { int c = i>>7, o = i&127;
    W[W1_OUTT + i] = ldin(outp_w, o*128 + c, bf); }
  for (int i = g0; i < 128; i += GS) W[W1_OUTB + i] = ldin(outp_b, i, bf);
}

// ---- weight conversion, phase 2 (into Bv+26000)
__global__ void k_conv2(const void* outp_w, const void* outp_b,
                        const void* conv3_w, const void* conv3_b, const void* beta,
                        const void* norm2_g, const void* conv4_w, const void* conv4_b,
                        const void* conv5_w, const void* conv5_b, const void* gamma,
                        float* __restrict__ W, const int* flagp) {
  const int bf = *flagp;
  const int g0 = blockIdx.x*256 + threadIdx.x, GS = gridDim.x*256;
  for (int i = g0; i < 16384; i += GS) { int c = i>>7, o = i&127;
    W[WB_OUTT + i] = ldin(outp_w, o*128 + c, bf); }
  for (int i = g0; i < 128; i += GS) W[WB_OUTB + i] = ldin(outp_b, i, bf);
  for (int i = g0; i < 8192; i += GS) { int c = i>>6, o = i&63;
    W[WB_C3T + i] = ldin(conv3_w, o*128 + c, bf); }
  for (int i = g0; i < 64; i += GS) { W[WB_C3B + i] = ldin(conv3_b, i, bf);
    W[WB_BETA + i] = ldin(beta, i, bf); }
  for (int i = g0; i < 16384; i += GS) { int c = i>>7, o = i&127;
    W[WB_W4T + i] = ldin(conv4_w, o*128 + c, bf) * ldin(norm2_g, c, bf); }
  for (int o = g0; o < 128; o += GS) { float s = 0.f;
    for (int c = 0; c < 128; ++c) s += ldin(conv4_w, o*128+c, bf) * ldin(norm2_g, c, bf);
    W[WB_RS4 + o] = s; W[WB_B4 + o] = ldin(conv4_b, o, bf); }
  for (int i = g0; i < 4096; i += GS) { int c = i>>6, o = i&63;
    W[WB_W5T + i] = ldin(conv5_w, o*64 + c, bf) * ldin(gamma, o, bf); }
  for (int i = g0; i < 64; i += GS)
    W[WB_B5G + i] = ldin(conv5_b, i, bf) * ldin(gamma, i, bf);
}

// ---- 1. LN(64) + pw1 + val -> h1, v  [8 waves; stats folded into pw1 loop]
__global__ __launch_bounds__(512, 6) void k_lnpw1v(const void* x, const float* __restrict__ W,
                                                   float* __restrict__ h1, float* __restrict__ vout,
                                                   const int* flagp) {
  const int bf = *flagp;
  const int tid = threadIdx.x, lane = tid & 63;
  const int pbase = blockIdx.x * PPB;
  const int b = pbase / HWn, rem0 = pbase % HWn;
  __shared__ float buf[8256];   // raw x (stride 65) -> h1 (stride 129) -> v (stride 129)
  for (int it = 0; it < 8; ++it) {
    int idx = it*512 + tid;     // 4096 = 64c x 64p
    int c = idx >> 6, p = idx & 63;
    buf[p*65 + c] = ldin(x, (long)(b*C0 + c)*HWn + rem0 + p, bf);
  }
  __syncthreads();
  const int obase = __builtin_amdgcn_readfirstlane((tid >> 6) * 16);
  float s = 0.f, s2 = 0.f;
  float acc[16] = {};
  for (int c = 0; c < 64; ++c) {
    const float a = buf[lane*65 + c];
    s += a; s2 += a*a;
    const float* __restrict__ wr = W + W1_PW1T + c*128 + obase;
    #pragma unroll
    for (int oi = 0; oi < 16; ++oi) acc[oi] += a * wr[oi];
  }
  const float mean = s * (1.f/64.f);
  const float rstd = rsqrtf(s2 * (1.f/64.f) - mean*mean + 1e-5f);
  __syncthreads();   // all stride-65 reads done
  #pragma unroll
  for (int oi = 0; oi < 16; ++oi)
    buf[lane*129 + obase + oi] =
      rstd*(acc[oi] - mean*W[W1_RS1 + obase + oi]) + W[W1_PB1 + obase + oi];
  __syncthreads();
  for (int it = 0; it < 4; ++it) {
    int idx = it*512 + tid;     // 2048 f4
    int p = idx >> 5, c4 = idx & 31;
    const float* sp = &buf[p*129 + c4*4];
    *(float4*)&h1[(long)(pbase+p)*128 + c4*4] = make_float4(sp[0],sp[1],sp[2],sp[3]);
  }
  float acc2[16] = {};
  for (int c = 0; c < 128; ++c) {
    const float a = buf[lane*129 + c];
    const float* __restrict__ wr = W + W1_VALT + c*128 + obase;
    #pragma unroll
    for (int oi = 0; oi < 16; ++oi) acc2[oi] += a * wr[oi];
  }
  __syncthreads();
  #pragma unroll
  for (int oi = 0; oi < 16; ++oi)
    buf[lane*129 + obase + oi] = acc2[oi] + W[W1_VB + obase + oi];
  __syncthreads();
  for (int it = 0; it < 4; ++it) {
    int idx = it*512 + tid;
    int p = idx >> 5, c4 = idx & 31;
    const float* sp = &buf[p*129 + c4*4];
    *(float4*)&vout[(long)(pbase+p)*128 + c4*4] = make_float4(sp[0],sp[1],sp[2],sp[3]);
  }
}

// ---- 2. depthwise 3x3 (8 ch/thread staging) + om head (128->108)  [8 waves]
__global__ __launch_bounds__(512, 6) void k_dwom4(const float* __restrict__ h1,
                                                  const float* __restrict__ W,
                                                  float* __restrict__ om) {
  const int tid = threadIdx.x, lane = tid & 63;
  const int pbase = blockIdx.x * PPB;
  const int b = pbase / HWn, rem0 = pbase % HWn;
  __shared__ float buf[8256];
  __shared__ float dww[1280];
  for (int i = tid; i < 1280; i += 512)
    dww[i] = (i < 1152) ? W[W1_DWC + i] : W[W1_DWB + i - 1152];
  __syncthreads();
  for (int it = 0; it < 2; ++it) {
    int idx = it*512 + tid;          // 1024 = 64 px x 16 slots(8ch)
    int p = idx >> 4, c = (idx & 15)*8;
    int rem = rem0 + p, h = rem / WW, w2 = rem % WW;
    float4 a0 = *(const float4*)&dww[1152 + c];
    float4 a1 = *(const float4*)&dww[1152 + c + 4];
    #pragma unroll
    for (int ky = 0; ky < 3; ++ky) {
      int hh = h + ky - 1;
      if (hh < 0 || hh >= HH) continue;
      #pragma unroll
      for (int kx = 0; kx < 3; ++kx) {
        int ww2 = w2 + kx - 1;
        if (ww2 < 0 || ww2 >= WW) continue;
        const float* __restrict__ hr = &h1[(long)(b*HWn + hh*WW + ww2)*128 + c];
        float4 h0 = *(const float4*)hr, h4 = *(const float4*)(hr + 4);
        const float* __restrict__ wv = &dww[(ky*3+kx)*128 + c];
        float4 w0 = *(const float4*)wv, w4 = *(const float4*)(wv + 4);
        a0.x += h0.x*w0.x; a0.y += h0.y*w0.y; a0.z += h0.z*w0.z; a0.w += h0.w*w0.w;
        a1.x += h4.x*w4.x; a1.y += h4.y*w4.y; a1.z += h4.z*w4.z; a1.w += h4.w*w4.w;
      }
    }
    float* d = &buf[p*129 + c];
    d[0]=a0.x; d[1]=a0.y; d[2]=a0.z; d[3]=a0.w;
    d[4]=a1.x; d[5]=a1.y; d[6]=a1.z; d[7]=a1.w;
  }
  __syncthreads();
  const int wv = tid >> 6;
  const int cnt = (wv < 4) ? 14 : 13;
  const int obase = __builtin_amdgcn_readfirstlane((wv < 4) ? wv*14 : 56 + (wv-4)*13);
  float acc[14] = {};
  for (int c = 0; c < 128; ++c) {
    const float a = buf[lane*129 + c];
    const float* __restrict__ wr = W + W1_OMT + c*108 + obase;
    #pragma unroll
    for (int oi = 0; oi < 14; ++oi) acc[oi] += a * wr[oi];  // oi=13 on wave7 reads next row start (valid mem), discarded
  }
  __syncthreads();
  #pragma unroll
  for (int oi = 0; oi < 14; ++oi)
    if (oi < cnt) buf[lane*129 + obase + oi] = acc[oi] + W[W1_OMB + obase + oi];
  __syncthreads();
  for (int it = 0; it < 14; ++it) {
    int idx = it*512 + tid;          // 6912 = 64*108
    if (idx < 6912) {
      int p = idx / 108, o = idx % 108;
      om[(long)(pbase+p)*108 + o] = buf[p*129 + o];
    }
  }
}

// ---- 3. deformable sampling: coord precompute in LDS + 8 ch/thread -> s [P][128]
__global__ __launch_bounds__(256) void k_samp8b(const float* __restrict__ v,
                                                const float* __restrict__ om,
                                                float* __restrict__ sout) {
  const int tid = threadIdx.x;
  const long pb = (long)blockIdx.x * 16;
  const int b = (int)(pb / HWn);
  __shared__ float pre[4608];   // 16px x 4g x 9k x {w0..w3, addr0..addr3}
  for (int idx = tid; idx < 576; idx += 256) {
    const int px = idx / 36, rest = idx % 36, g = rest / 9, k = rest % 9;
    const long p = pb + px;
    const int rem = (int)(p % HWn), h = rem / WW, w = rem % WW;
    const float offx = om[p*108 + g*27 + k*3 + 0];
    const float offy = om[p*108 + g*27 + k*3 + 1];
    const float m    = om[p*108 + g*27 + k*3 + 2];
    const float pxf = (float)(w + (k % 3)) + offx;   // padded coords, Wp=162
    const float pyf = (float)(h + (k / 3)) + offy;
    const float x0f = floorf(pxf), y0f = floorf(pyf);
    const float tx = pxf - x0f, ty = pyf - y0f;
    const int x0 = (int)x0f, y0 = (int)y0f;
    float wv[4]; int av[4];
    #pragma unroll
    for (int dy = 0; dy < 2; ++dy)
      #pragma unroll
      for (int dx = 0; dx < 2; ++dx) {
        const int xi = x0 + dx, yi = y0 + dy;
        const bool ok = (xi >= 1 && xi <= WW && yi >= 1 && yi <= HH);
        const float wq = ok ? (dx ? tx : 1.f - tx) * (dy ? ty : 1.f - ty) * m : 0.f;
        const int xc = min(max(xi, 1), WW), yc = min(max(yi, 1), HH);
        wv[dy*2+dx] = wq; av[dy*2+dx] = (yc-1)*WW + (xc-1);
      }
    *(float4*)&pre[idx*8]     = make_float4(wv[0], wv[1], wv[2], wv[3]);
    *(float4*)&pre[idx*8 + 4] = make_float4(__int_as_float(av[0]), __int_as_float(av[1]),
                                            __int_as_float(av[2]), __int_as_float(av[3]));
  }
  __syncthreads();
  const int p16 = tid >> 4, slot = tid & 15;
  const int g = slot >> 2, c = g*32 + (slot & 3)*8;
  const long p = pb + p16;
  const float* __restrict__ vb = v + (long)b*HWn*128;
  const int base0 = ((p16*4 + g)*9)*8;
  float4 a0 = make_float4(0.f,0.f,0.f,0.f), a1 = make_float4(0.f,0.f,0.f,0.f);
  #pragma unroll
  for (int k = 0; k < 9; ++k) {
    const float4 wq4 = *(const float4*)&pre[base0 + k*8];
    const float4 ad4 = *(const float4*)&pre[base0 + k*8 + 4];
    #pragma unroll
    for (int j = 0; j < 4; ++j) {
      const float wq = (j==0)?wq4.x:(j==1)?wq4.y:(j==2)?wq4.z:wq4.w;
      const int pix = __float_as_int((j==0)?ad4.x:(j==1)?ad4.y:(j==2)?ad4.z:ad4.w);
      const float* __restrict__ vr = vb + (long)pix*128 + c;
      const float4 v0 = *(const float4*)vr;
      const float4 v1 = *(const float4*)(vr + 4);
      a0.x += wq*v0.x; a0.y += wq*v0.y; a0.z += wq*v0.z; a0.w += wq*v0.w;
      a1.x += wq*v1.x; a1.y += wq*v1.y; a1.z += wq*v1.z; a1.w += wq*v1.w;
    }
  }
  *(float4*)&sout[p*128 + c]     = a0;
  *(float4*)&sout[p*128 + c + 4] = a1;
}

// ---- 4. outp + SimpleGate -> f [64][PN] (CM), gate pairs in registers  [8 waves]
__global__ __launch_bounds__(512, 6) void k_outp(const float* __restrict__ s,
                                                 const float* __restrict__ wT,
                                                 const float* __restrict__ bias,
                                                 float* __restrict__ f) {
  const int tid = threadIdx.x, lane = tid & 63;
  const int pbase = blockIdx.x * PPB;
  __shared__ float buf[8256];
  for (int it = 0; it < 4; ++it) {
    int idx = it*512 + tid;     // 2048 f4
    int p = idx >> 5, c4 = idx & 31;
    float4 v = *(const float4*)&s[(long)(pbase+p)*128 + c4*4];
    float* d = &buf[p*129 + c4*4];
    d[0]=v.x; d[1]=v.y; d[2]=v.z; d[3]=v.w;
  }
  __syncthreads();
  const int gb = __builtin_amdgcn_readfirstlane((tid >> 6) * 8);
  float accL[8] = {}, accH[8] = {};
  for (int c = 0; c < 128; ++c) {
    const float a = buf[lane*129 + c];
    const float* __restrict__ wrL = wT + c*128 + gb;
    const float* __restrict__ wrH = wrL + 64;
    #pragma unroll
    for (int oi = 0; oi < 8; ++oi) { accL[oi] += a*wrL[oi]; accH[oi] += a*wrH[oi]; }
  }
  #pragma unroll
  for (int oi = 0; oi < 8; ++oi)
    f[(long)(gb+oi)*PN + pbase + lane] =
      (accL[oi] + bias[gb+oi]) * (accH[oi] + bias[64+gb+oi]);
}

// ---- 5a. pool: one block per (b, ch) over CM rows -> pooled[256]
__global__ __launch_bounds__(256) void k_pool(const float* __restrict__ fL,
                                              const float* __restrict__ fR,
                                              float* __restrict__ pooled) {
  const int blk = blockIdx.x;                 // b*128 + ch
  const int b = blk >> 7, ch = blk & 127;
  const float* __restrict__ row = ((ch < 64) ? fL : fR) + (long)(ch & 63)*PN + (long)b*HWn;
  const float4* __restrict__ r4 = (const float4*)row;
  float s = 0.f;
  for (int i = threadIdx.x; i < HWn/4; i += 256) {
    float4 t = r4[i]; s += (t.x + t.y) + (t.z + t.w);
  }
  __shared__ float red[256];
  red[threadIdx.x] = s; __syncthreads();
  for (int k = 128; k > 0; k >>= 1) { if (threadIdx.x < k) red[threadIdx.x] += red[threadIdx.x+k]; __syncthreads(); }
  if (threadIdx.x == 0) pooled[blk] = red[0] / (float)HWn;
}

// ---- 5b. pooled -> scale
__global__ __launch_bounds__(256) void k_scale(const float* __restrict__ pooled,
                                               const void* sca_w, const void* sca_b,
                                               float* __restrict__ scale, const int* flagp) {
  const int bf = *flagp;
  const int t = threadIdx.x, b = t >> 7, o = t & 127;
  float acc = ldin(sca_b, o, bf);
  for (int c = 0; c < 128; ++c) acc += pooled[b*128 + c] * ldin(sca_w, o*128 + c, bf);
  scale[b*128 + o] = acc;
}

// ---- 6. FUSED: f*scale -> conv3 -> y (LDS) -> LN(128)+conv4+SG+conv5+residual -> dout
__global__ __launch_bounds__(512) void k_c3f2(const float* __restrict__ fL,
                                              const float* __restrict__ fR,
                                              const float* __restrict__ scaleP,
                                              const float* __restrict__ W,
                                              const void* x_l, const void* x_r,
                                              void* dout, const int* flagp) {
  const int bf = *flagp;
  const int tid = threadIdx.x, lane = tid & 63, wv = tid >> 6;
  const int pbase = blockIdx.x * 64;
  const int b = pbase / HWn, rem = pbase % HWn + lane;
  __shared__ float act[8256];    // f*scale (stride 129) -> y (same tile)
  __shared__ float sgs[4160];    // SimpleGate output (stride 65)
  __shared__ float scl[128];
  if (tid < 128) scl[tid] = scaleP[b*128 + tid];
  __syncthreads();
  // stage f*scale: [64px][128ch], coalesced CM reads
  for (int it = 0; it < 16; ++it) {
    int idx = it*512 + tid;
    int c = idx >> 6, pp = idx & 63;
    float fv = (c < 64) ? fL[(long)c*PN + pbase + pp] : fR[(long)(c-64)*PN + pbase + pp];
    act[pp*129 + c] = fv * scl[c];
  }
  __syncthreads();
  const int gb = __builtin_amdgcn_readfirstlane(wv * 8);
  // issue x residual loads early (independent of act) to hide HBM latency under conv3
  float xv[8], xrv[8];
  #pragma unroll
  for (int oi = 0; oi < 8; ++oi) {
    xv[oi]  = ldin(x_l, (long)(b*C0 + gb + oi)*HWn + rem, bf);
    xrv[oi] = ldin(x_r, (long)(b*C0 + gb + oi)*HWn + rem, bf);
  }
  // conv3 (128->64): wave wv computes outputs gb..gb+7 for pixel lane
  float acc3[8] = {};
  for (int c = 0; c < 128; ++c) {
    const float a = act[lane*129 + c];
    const float* __restrict__ wr = W + WB_C3T + c*64 + gb;
    #pragma unroll
    for (int oi = 0; oi < 8; ++oi) acc3[oi] += a * wr[oi];
  }
  __syncthreads();   // all conv3 act reads done before overwrite
  // y = x + x3*beta -> back into act: rows 0-63 = L, 64-127 = R
  #pragma unroll
  for (int oi = 0; oi < 8; ++oi) {
    const float x3b = (acc3[oi] + W[WB_C3B + gb + oi]) * W[WB_BETA + gb + oi];
    act[lane*129 + gb + oi]       = xv[oi]  + x3b;
    act[lane*129 + 64 + gb + oi]  = xrv[oi] + x3b;
  }
  __syncthreads();
  // LN(128) + conv4 single pass (LN folded into weights)
  float s = 0.f, s2 = 0.f;
  float accL[8] = {}, accH[8] = {};
  for (int c = 0; c < 128; ++c) {
    const float a = act[lane*129 + c];
    s += a; s2 += a*a;
    const float* __restrict__ wrL = W + WB_W4T + c*128 + gb;
    const float* __restrict__ wrH = wrL + 64;
    #pragma unroll
    for (int oi = 0; oi < 8; ++oi) { accL[oi] += a*wrL[oi]; accH[oi] += a*wrH[oi]; }
  }
  const float mean = s * (1.f/128.f);
  const float rstd = rsqrtf(s2*(1.f/128.f) - mean*mean + 1e-5f);
  #pragma unroll
  for (int oi = 0; oi < 8; ++oi) {
    float tl = rstd*(accL[oi] - mean*W[WB_RS4+gb+oi])    + W[WB_B4+gb+oi];
    float th = rstd*(accH[oi] - mean*W[WB_RS4+64+gb+oi]) + W[WB_B4+64+gb+oi];
    sgs[lane*65 + gb + oi] = tl * th;
  }
  __syncthreads();
  // conv5 (64->64, gamma folded) + residual from act + NCHW store
  float acc5[8] = {};
  #pragma unroll 4
  for (int c = 0; c < 64; ++c) {
    const float a = sgs[lane*65 + c];
    const float* __restrict__ wr = W + WB_W5T + c*64 + gb;
    #pragma unroll
    for (int oi = 0; oi < 8; ++oi) acc5[oi] += a * wr[oi];
  }
  #pragma unroll
  for (int oi = 0; oi < 8; ++oi) {
    const int o = gb + oi;
    const float z = acc5[oi] + W[WB_B5G + o];
    const float outL = act[lane*129 + o] + z;
    const float outR = act[lane*129 + 64 + o] + z;
    stout(dout, (long)(b*C0 + o)*HWn + rem, outL, bf);
    stout(dout, (long)BN*C0*HWn + (long)(b*C0 + o)*HWn + rem, outR, bf);
  }
}

extern "C" void kernel_launch(void* const* d_in, const int* in_sizes, int n_in,
                              void* d_out, int out_size, void* d_ws, size_t ws_size,
                              hipStream_t stream) {
  const void* x_l    = d_in[0];
  const void* x_r    = d_in[1];
  const void* ln1_g  = d_in[2];
  const void* pw1_w  = d_in[3];
  const void* pw1_b  = d_in[4];
  const void* val_w  = d_in[5];
  const void* val_b  = d_in[6];
  const void* dwc_w  = d_in[7];
  const void* dwc_b  = d_in[8];
  const void* om_w   = d_in[9];
  const void* om_b   = d_in[10];
  const void* outp_w = d_in[11];
  const void* outp_b = d_in[12];
  const void* sca_w  = d_in[13];
  const void* sca_b  = d_in[14];
  const void* conv3_w = d_in[15];
  const void* conv3_b = d_in[16];
  const void* norm2_g = d_in[17];
  const void* conv4_w = d_in[18];
  const void* conv4_b = d_in[19];
  const void* conv5_w = d_in[20];
  const void* conv5_b = d_in[21];
  const void* beta   = d_in[22];
  const void* gamma  = d_in[23];

  int* flag  = (int*)d_ws;
  float* wsf = (float*)((char*)d_ws + 1024);
  // Regions: A = h1/s (PM); Bv = v (PM) -> pooled/scale/WB; Cm = om (PM);
  //          fL/fR = f (CM); W1 in fR until side-1 k_outp; WB in dead v.
  float* A  = wsf;
  float* Bv = wsf + S128;
  float* Cm = wsf + 2*S128;
  float* fL = wsf + 2*S128 + S108;
  float* fR = fL + S64v;
  float* W1 = fR;
  float* WB = Bv + 26000;
  float* pooled = Bv;                    // 256 floats
  float* scaleP = Bv + 512;              // 256 floats (disjoint from WB at +26000)

  hipLaunchKernelGGL(k_conv1, dim3(64), dim3(256), 0, stream,
                     pw1_w, ln1_g, pw1_b, val_w, val_b, dwc_w, dwc_b,
                     om_w, om_b, outp_w, outp_b, W1, flag);

  // side 0 (pixel-major pipeline)
  hipLaunchKernelGGL(k_lnpw1v, dim3(NB),    dim3(512), 0, stream, x_l, W1, A, Bv, flag);
  hipLaunchKernelGGL(k_dwom4,  dim3(NB),    dim3(512), 0, stream, A, W1, Cm);
  hipLaunchKernelGGL(k_samp8b, dim3(PN/16), dim3(256), 0, stream, Bv, Cm, A);
  hipLaunchKernelGGL(k_outp,   dim3(NB),    dim3(512), 0, stream, A, W1 + W1_OUTT, W1 + W1_OUTB, fL);
  // side 1
  hipLaunchKernelGGL(k_lnpw1v, dim3(NB),    dim3(512), 0, stream, x_r, W1, A, Bv, flag);
  hipLaunchKernelGGL(k_dwom4,  dim3(NB),    dim3(512), 0, stream, A, W1, Cm);
  hipLaunchKernelGGL(k_samp8b, dim3(PN/16), dim3(256), 0, stream, Bv, Cm, A);
  hipLaunchKernelGGL(k_conv2,  dim3(64),    dim3(256), 0, stream,
                     outp_w, outp_b, conv3_w, conv3_b, beta, norm2_g,
                     conv4_w, conv4_b, conv5_w, conv5_b, gamma, WB, flag);
  hipLaunchKernelGGL(k_outp,   dim3(NB),    dim3(512), 0, stream, A, WB + WB_OUTT, WB + WB_OUTB, fR);

  // phase 2 (channel-major + fused epilogue)
  hipLaunchKernelGGL(k_pool,   dim3(256),   dim3(256), 0, stream, fL, fR, pooled);
  hipLaunchKernelGGL(k_scale,  dim3(1),     dim3(256), 0, stream, pooled, sca_w, sca_b, scaleP, flag);
  hipLaunchKernelGGL(k_c3f2,   dim3(800),   dim3(512), 0, stream, fL, fR, scaleP, WB,
                     x_l, x_r, d_out, flag);
}